// Round 7
// baseline (855.916 us; speedup 1.0000x reference)
//
#include <hip/hip_runtime.h>

typedef _Float16 half8 __attribute__((ext_vector_type(8)));
typedef _Float16 half4 __attribute__((ext_vector_type(4)));
typedef float floatx4 __attribute__((ext_vector_type(4)));

// ---------------- small helpers ----------------
__global__ __launch_bounds__(256) void zero_i32(int* __restrict__ p, int n) {
    int i = blockIdx.x * 256 + threadIdx.x;
    if (i < n) p[i] = 0;
}

__global__ __launch_bounds__(256) void hist_dst(const int* __restrict__ dst,
                                                int* __restrict__ count, int E) {
    int e = blockIdx.x * 256 + threadIdx.x;
    if (e < E) atomicAdd(&count[dst[e]], 1);
}

__global__ __launch_bounds__(256) void cast_f32_f16(const float* __restrict__ in,
                                                    _Float16* __restrict__ out, int n4) {
    int i = blockIdx.x * 256 + threadIdx.x;
    if (i < n4) {
        float4 v = *(const float4*)&in[(size_t)i * 4];
        half4 h = { (_Float16)v.x, (_Float16)v.y, (_Float16)v.z, (_Float16)v.w };
        *(half4*)&out[(size_t)i * 4] = h;
    }
}

// tiled transpose+cast: W[K x N] fp32 -> WT[N x K] fp16. 32x32 tiles via LDS.
__global__ __launch_bounds__(256) void transpose_cast_tiled(
    const float* __restrict__ W, _Float16* __restrict__ WT, int K, int N)
{
    __shared__ _Float16 t[32][33];
    const int k0 = blockIdx.x * 32, n0 = blockIdx.y * 32;
    const int tx = threadIdx.x & 31, ty = threadIdx.x >> 5;
    #pragma unroll
    for (int i = 0; i < 4; ++i) {
        int k = k0 + ty + i * 8, n = n0 + tx;
        float v = (k < K && n < N) ? W[(size_t)k * N + n] : 0.0f;
        t[ty + i * 8][tx] = (_Float16)v;
    }
    __syncthreads();
    #pragma unroll
    for (int i = 0; i < 4; ++i) {
        int n = n0 + ty + i * 8, k = k0 + tx;
        if (n < N && k < K) WT[(size_t)n * K + k] = t[tx][ty + i * 8];
    }
}

// ---------------- scan for CSR (also emits dinv) ----------------
__global__ __launch_bounds__(256) void scan_block(const int* __restrict__ count,
                                                  int* __restrict__ incl,
                                                  int* __restrict__ blocksum,
                                                  float* __restrict__ dinv, int n) {
    __shared__ int tmp[256];
    int t = threadIdx.x;
    int i = blockIdx.x * 256 + t;
    int v = (i < n) ? count[i] : 0;
    if (i < n) dinv[i] = rsqrtf(1.0f + (float)v);
    tmp[t] = v;
    __syncthreads();
    for (int off = 1; off < 256; off <<= 1) {
        int x = (t >= off) ? tmp[t - off] : 0;
        __syncthreads();
        tmp[t] += x;
        __syncthreads();
    }
    if (i < n) incl[i] = tmp[t];
    if (t == 255) blocksum[blockIdx.x] = tmp[255];
}

__global__ __launch_bounds__(256) void scan_top(const int* __restrict__ blocksum,
                                                int* __restrict__ blockoff, int nb) {
    __shared__ int tmp[256];
    int t = threadIdx.x;
    int v = (t < nb) ? blocksum[t] : 0;
    tmp[t] = v;
    __syncthreads();
    for (int off = 1; off < 256; off <<= 1) {
        int x = (t >= off) ? tmp[t - off] : 0;
        __syncthreads();
        tmp[t] += x;
        __syncthreads();
    }
    if (t < nb) blockoff[t] = tmp[t] - v;
}

__global__ __launch_bounds__(256) void make_rowptr(const int* __restrict__ incl,
                                                   const int* __restrict__ count,
                                                   const int* __restrict__ blockoff,
                                                   int* __restrict__ rowptr,
                                                   int* __restrict__ cursor, int n) {
    int i = blockIdx.x * 256 + threadIdx.x;
    if (i < n) {
        int r = incl[i] - count[i] + blockoff[blockIdx.x];
        rowptr[i] = r;
        cursor[i] = r;
    }
}

// packed (src, norm) -> one 8B store per edge
__global__ __launch_bounds__(256) void scatter_perm(const int* __restrict__ src,
                                                    const int* __restrict__ dst,
                                                    const float* __restrict__ dinv,
                                                    int* __restrict__ cursor,
                                                    int2* __restrict__ sorted_meta, int E) {
    int e = blockIdx.x * 256 + threadIdx.x;
    if (e < E) {
        int d = dst[e], s = src[e];
        int slot = atomicAdd(&cursor[d], 1);
        sorted_meta[slot] = make_int2(s, __float_as_int(dinv[s] * dinv[d]));
    }
}

// ---------------- barrier-free register-direct fp16 MFMA GEMM ----------------
// C[M x Nrows] = A[M x K](lda) @ BT[Nrows x K]^T. No LDS, no __syncthreads:
// A and B fragments (layout m=lane&15, k=q*8+j) loaded straight from global;
// 2-stage register ping-pong pipelines loads over MFMAs (fine-grained vmcnt).
// XCD swizzle: blockIdx%8 == m_tile%8 so all n-tiles of an m-tile share one
// XCD's L2 (A fetched once per XCD partition, weights L2-resident).
// Block = 4 waves (2x2), wave = 64x64, block tile 128x128.
template<bool DUAL>
__global__ __launch_bounds__(256) void gemm_reg(
    const _Float16* __restrict__ A, int lda,
    const _Float16* __restrict__ BT, int Nrows, int K,
    const float* __restrict__ bias0, const float* __restrict__ bias1,
    _Float16* __restrict__ lin_h, _Float16* __restrict__ hw,
    float* __restrict__ Cf, int ldc,
    int M, int m_tiles, int n_tiles)
{
    const int b     = blockIdx.x;
    const int x     = b & 7;
    const int inner = b >> 3;
    const int n_t   = inner % n_tiles;
    const int m_t   = (inner / n_tiles) * 8 + x;
    if (m_t >= m_tiles) return;

    const int bm = m_t * 128, bn = n_t * 128;
    const int wave = threadIdx.x >> 6, lane = threadIdx.x & 63;
    const int q = lane >> 4, r = lane & 15;
    const int wm = (wave & 1) * 64, wn = (wave >> 1) * 64;

    const _Float16* ap[4];
    const _Float16* bp[4];
    #pragma unroll
    for (int mi = 0; mi < 4; ++mi) {
        int gm = bm + wm + mi * 16 + r; if (gm > M - 1) gm = M - 1;
        ap[mi] = A + (size_t)gm * lda + q * 8;
    }
    #pragma unroll
    for (int ni = 0; ni < 4; ++ni) {
        int gn = bn + wn + ni * 16 + r; if (gn > Nrows - 1) gn = Nrows - 1;
        bp[ni] = BT + (size_t)gn * K + q * 8;
    }

    floatx4 acc[4][4] = {};
    half8 a0[4], b0[4], a1[4], b1[4];

#define MFMA16(AF, BF)                                                      \
    _Pragma("unroll")                                                       \
    for (int mi = 0; mi < 4; ++mi)                                          \
        _Pragma("unroll")                                                   \
        for (int ni = 0; ni < 4; ++ni)                                      \
            acc[mi][ni] = __builtin_amdgcn_mfma_f32_16x16x32_f16(           \
                AF[mi], BF[ni], acc[mi][ni], 0, 0, 0);

    #pragma unroll
    for (int i = 0; i < 4; ++i) { a0[i] = *(const half8*)(ap[i]); b0[i] = *(const half8*)(bp[i]); }

    int k0 = 0;
    for (; k0 < K - 64; k0 += 64) {
        #pragma unroll
        for (int i = 0; i < 4; ++i) { a1[i] = *(const half8*)(ap[i] + 32); b1[i] = *(const half8*)(bp[i] + 32); }
        MFMA16(a0, b0);
        #pragma unroll
        for (int i = 0; i < 4; ++i) { a0[i] = *(const half8*)(ap[i] + 64); b0[i] = *(const half8*)(bp[i] + 64); }
        MFMA16(a1, b1);
        #pragma unroll
        for (int i = 0; i < 4; ++i) { ap[i] += 64; bp[i] += 64; }
    }
    // tail: k0 == K-64
    #pragma unroll
    for (int i = 0; i < 4; ++i) { a1[i] = *(const half8*)(ap[i] + 32); b1[i] = *(const half8*)(bp[i] + 32); }
    MFMA16(a0, b0);
    MFMA16(a1, b1);
#undef MFMA16

    // epilogue: C/D layout col = r (+16*ni), row = q*4+reg.
    // ni-innermost store order: 4 consecutive stores cover a 128B row segment.
    if (DUAL) {
        const bool islin = (bn < 256);
        _Float16* dstp = islin ? lin_h : hw;
        float badd[4];
        #pragma unroll
        for (int ni = 0; ni < 4; ++ni) {
            int col = bn + wn + ni * 16 + r;
            badd[ni] = islin ? (bias0[col] + bias1[col]) : 0.0f;
        }
        const int cbase = islin ? (bn + wn) : (bn - 256 + wn);
        #pragma unroll
        for (int mi = 0; mi < 4; ++mi)
            #pragma unroll
            for (int reg = 0; reg < 4; ++reg) {
                int gm = bm + wm + mi * 16 + q * 4 + reg;
                if (gm >= M) continue;
                #pragma unroll
                for (int ni = 0; ni < 4; ++ni)
                    dstp[(size_t)gm * 256 + cbase + ni * 16 + r] =
                        (_Float16)(acc[mi][ni][reg] + badd[ni]);
            }
    } else {
        float badd[4];
        #pragma unroll
        for (int ni = 0; ni < 4; ++ni) {
            int col = bn + wn + ni * 16 + r;
            badd[ni] = (bias0 && col < Nrows) ? bias0[col] : 0.0f;
        }
        #pragma unroll
        for (int mi = 0; mi < 4; ++mi)
            #pragma unroll
            for (int reg = 0; reg < 4; ++reg) {
                int gm = bm + wm + mi * 16 + q * 4 + reg;
                if (gm >= M) continue;
                #pragma unroll
                for (int ni = 0; ni < 4; ++ni) {
                    int col = bn + wn + ni * 16 + r;
                    if (col < Nrows)
                        Cf[(size_t)gm * ldc + col] = acc[mi][ni][reg] + badd[ni];
                }
            }
    }
}

// ---------------- fused CSR aggregate, feature-split across XCDs ----------------
__global__ __launch_bounds__(256) void aggregate_csr(
    const int* __restrict__ rowptr, const int* __restrict__ count,
    const int2* __restrict__ sorted_meta,
    const float* __restrict__ dinv,
    const _Float16* __restrict__ hw,
    const _Float16* __restrict__ lin_h,
    _Float16* __restrict__ jk_col, int n)
{
    const int bx    = blockIdx.x;
    const int xslot = bx & 7;
    const int half  = xslot >> 2;
    const int chunk = ((bx >> 3) << 2) + (xslot & 3);
    const int wave  = threadIdx.x >> 6;
    const int lane  = threadIdx.x & 63;
    const int i     = chunk * 4 + wave;
    if (i >= n) return;

    const int qw = lane >> 4;
    const int fl = lane & 15;
    const int fbase = half * 128 + fl * 8;

    const int start = rowptr[i];
    const int deg   = count[i];

    float accf[8] = {};
    if (qw == 0) {
        half8 l8 = *(const half8*)&lin_h[(size_t)i * 256 + fbase];
        #pragma unroll
        for (int t = 0; t < 8; ++t) accf[t] = (float)l8[t];
    } else if (qw == 1) {
        float di = dinv[i];
        float sn = di * di;
        half8 s8 = *(const half8*)&hw[(size_t)i * 256 + fbase];
        #pragma unroll
        for (int t = 0; t < 8; ++t) accf[t] = (float)s8[t] * sn;
    }

    for (int base = 0; base < deg; base += 64) {
        int m = deg - base;
        if (m > 64) m = 64;
        int2 meta = make_int2(0, 0);
        if (lane < m) meta = sorted_meta[start + base + lane];

        for (int j = 0; j < m; j += 16) {
            half8 hv[4];
            float nm[4];
            #pragma unroll
            for (int k2 = 0; k2 < 4; ++k2) {
                int e   = j + k2 * 4 + qw;
                int idx = (e < m) ? e : (m - 1);
                int s   = __shfl(meta.x, idx, 64);
                int nmb = __shfl(meta.y, idx, 64);
                nm[k2]  = (e < m) ? __int_as_float(nmb) : 0.0f;
                hv[k2]  = *(const half8*)&hw[(size_t)s * 256 + fbase];
            }
            #pragma unroll
            for (int k2 = 0; k2 < 4; ++k2)
                #pragma unroll
                for (int t = 0; t < 8; ++t)
                    accf[t] = fmaf((float)hv[k2][t], nm[k2], accf[t]);
        }
    }

    #pragma unroll
    for (int t = 0; t < 8; ++t) {
        accf[t] += __shfl_xor(accf[t], 16, 64);
        accf[t] += __shfl_xor(accf[t], 32, 64);
    }

    if (qw == 0) {
        half8 o;
        #pragma unroll
        for (int t = 0; t < 8; ++t) o[t] = (_Float16)fmaxf(accf[t], 0.0f);
        *(half8*)&jk_col[(size_t)i * 1024 + fbase] = o;
    }
}

extern "C" void kernel_launch(void* const* d_in, const int* in_sizes, int n_in,
                              void* d_out, int out_size, void* d_ws, size_t ws_size,
                              hipStream_t stream) {
    const float* x        = (const float*)d_in[0];
    const int*   ei       = (const int*)d_in[1];
    const float* in_gc_W  = (const float*)d_in[2];
    const float* in_gc_b  = (const float*)d_in[3];
    const float* in_lin_W = (const float*)d_in[4];
    const float* in_lin_b = (const float*)d_in[5];
    const float* convs_W  = (const float*)d_in[6];
    const float* convs_b  = (const float*)d_in[7];
    const float* lins_W   = (const float*)d_in[8];
    const float* lins_b   = (const float*)d_in[9];
    const float* out_W    = (const float*)d_in[10];
    const float* out_b    = (const float*)d_in[11];

    const int N = 50000;
    const int E = in_sizes[1] / 2;
    const int F = 512, H = 256, L = 4, NC = 40;

    const int* src = ei;
    const int* dst = ei + E;

    char* ws = (char*)d_ws;
    auto carve = [&](size_t bytes) { void* p = ws; ws += (bytes + 255) & ~(size_t)255; return p; };
    float*    dinv        = (float*)carve((size_t)N * 4);
    int*      count       = (int*)  carve((size_t)N * 4);
    int*      incl        = (int*)  carve((size_t)N * 4);
    int*      rowptr      = (int*)  carve((size_t)N * 4);
    int*      cursor      = (int*)  carve((size_t)N * 4);
    int*      blocksum    = (int*)  carve(256 * 4);
    int*      blockoff    = (int*)  carve(256 * 4);
    int2*     sorted_meta = (int2*) carve((size_t)E * 8);
    _Float16* xh          = (_Float16*)carve((size_t)N * F * 2);
    _Float16* w0comb      = (_Float16*)carve((size_t)512 * F * 2);
    _Float16* wcomb       = (_Float16*)carve((size_t)3 * 512 * H * 2);
    _Float16* outWT       = (_Float16*)carve((size_t)NC * H * L * 2);
    _Float16* lin_h       = (_Float16*)carve((size_t)N * H * 2);
    _Float16* hw          = (_Float16*)carve((size_t)N * H * 2);
    _Float16* jk_h        = (_Float16*)carve((size_t)N * H * L * 2);
    float*    out         = (float*)d_out;

    const int nbN = (N + 255) / 256;
    const int nbE = (E + 255) / 256;

    // 1) CSR build + dinv
    zero_i32<<<nbN, 256, 0, stream>>>(count, N);
    hist_dst<<<nbE, 256, 0, stream>>>(dst, count, E);
    scan_block<<<nbN, 256, 0, stream>>>(count, incl, blocksum, dinv, N);
    scan_top<<<1, 256, 0, stream>>>(blocksum, blockoff, nbN);
    make_rowptr<<<nbN, 256, 0, stream>>>(incl, count, blockoff, rowptr, cursor, N);
    scatter_perm<<<nbE, 256, 0, stream>>>(src, dst, dinv, cursor, sorted_meta, E);

    // 2) casts / tiled transposes
    cast_f32_f16<<<(N * F / 4 + 255) / 256, 256, 0, stream>>>(x, xh, N * F / 4);
    {
        dim3 tg((F + 31) / 32, (H + 31) / 32);
        transpose_cast_tiled<<<tg, 256, 0, stream>>>(in_lin_W, w0comb,                F, H);
        transpose_cast_tiled<<<tg, 256, 0, stream>>>(in_gc_W,  w0comb + (size_t)H * F, F, H);
        dim3 th((H + 31) / 32, (H + 31) / 32);
        for (int l = 0; l < 3; ++l) {
            _Float16* wl = wcomb + (size_t)l * 512 * H;
            transpose_cast_tiled<<<th, 256, 0, stream>>>(lins_W  + (size_t)l * H * H, wl,                 H, H);
            transpose_cast_tiled<<<th, 256, 0, stream>>>(convs_W + (size_t)l * H * H, wl + (size_t)H * H, H, H);
        }
        dim3 to((H * L + 31) / 32, (NC + 31) / 32);
        transpose_cast_tiled<<<to, 256, 0, stream>>>(out_W, outWT, H * L, NC);
    }

    const int m_tiles = (N + 127) / 128;                  // 391
    const int m_grps  = (m_tiles + 7) / 8;                // 49
    const int dual_blocks = 8 * m_grps * 4;               // 1568
    const int out_blocks  = 8 * m_grps * 1;               // 392
    const int agg_blocks  = 2 * ((N + 3) / 4);            // 25000

    // 3) layers
    for (int l = 0; l < L; ++l) {
        const _Float16* Ah = (l == 0) ? xh : (jk_h + (size_t)(l - 1) * H);
        int lda            = (l == 0) ? F : H * L;
        int K              = (l == 0) ? F : H;
        const _Float16* BT = (l == 0) ? w0comb : (wcomb + (size_t)(l - 1) * 512 * H);
        const float* gcB   = (l == 0) ? in_gc_b  : (convs_b + (size_t)(l - 1) * H);
        const float* liB   = (l == 0) ? in_lin_b : (lins_b  + (size_t)(l - 1) * H);

        gemm_reg<true><<<dual_blocks, 256, 0, stream>>>(Ah, lda, BT, 512, K, liB, gcB,
                                                        lin_h, hw, nullptr, 0, N, m_tiles, 4);
        aggregate_csr<<<agg_blocks, 256, 0, stream>>>(rowptr, count, sorted_meta,
                                                      dinv, hw, lin_h, jk_h + (size_t)l * H, N);
    }

    // 4) out = jk_h @ out_W + out_b
    gemm_reg<false><<<out_blocks, 256, 0, stream>>>(jk_h, H * L, outWT, NC, H * L, out_b, nullptr,
                                                    nullptr, nullptr, out, NC, N, m_tiles, 1);
}

// Round 8
// 816.922 us; speedup vs baseline: 1.0477x; 1.0477x over previous
//
#include <hip/hip_runtime.h>

typedef _Float16 half8 __attribute__((ext_vector_type(8)));
typedef _Float16 half4 __attribute__((ext_vector_type(4)));
typedef float floatx4 __attribute__((ext_vector_type(4)));

// async global->LDS, 16B per lane. LDS dest is wave-uniform base + lane*16.
__device__ __forceinline__ void gld16(const _Float16* g, _Float16* lds_base) {
    __builtin_amdgcn_global_load_lds(
        (const __attribute__((address_space(1))) unsigned int*)g,
        (__attribute__((address_space(3))) unsigned int*)lds_base,
        16, 0, 0);
}

// ---------------- fused x-cast (fp32->fp16, 16B stores) + count zeroing ----
__global__ __launch_bounds__(256) void cast_x_zero(const float* __restrict__ in,
                                                   _Float16* __restrict__ out, int n8,
                                                   int* __restrict__ count, int nzero) {
    int i = blockIdx.x * 256 + threadIdx.x;
    if (i < n8) {
        float4 v0 = *(const float4*)&in[(size_t)i * 8];
        float4 v1 = *(const float4*)&in[(size_t)i * 8 + 4];
        half8 h = { (_Float16)v0.x, (_Float16)v0.y, (_Float16)v0.z, (_Float16)v0.w,
                    (_Float16)v1.x, (_Float16)v1.y, (_Float16)v1.z, (_Float16)v1.w };
        *(half8*)&out[(size_t)i * 8] = h;
    }
    if (i < nzero) count[i] = 0;
}

__global__ __launch_bounds__(256) void hist_dst(const int* __restrict__ dst,
                                                int* __restrict__ count, int E) {
    int e = blockIdx.x * 256 + threadIdx.x;
    if (e < E) atomicAdd(&count[dst[e]], 1);
}

// ---------------- batched tiled transpose+cast kernels ----------------
// core: W[K x N] fp32 -> WT[N x K] fp16, 32x32 LDS tile
__device__ __forceinline__ void tc_tile(const float* W, _Float16* WT, int K, int N,
                                        int k0, int n0, int tx, int ty) {
    __shared__ _Float16 t[32][33];
    #pragma unroll
    for (int i = 0; i < 4; ++i) {
        int k = k0 + ty + i * 8, n = n0 + tx;
        float v = (k < K && n < N) ? W[(size_t)k * N + n] : 0.0f;
        t[ty + i * 8][tx] = (_Float16)v;
    }
    __syncthreads();
    #pragma unroll
    for (int i = 0; i < 4; ++i) {
        int n = n0 + ty + i * 8, k = k0 + tx;
        if (n < N && k < K) WT[(size_t)n * K + k] = t[tx][ty + i * 8];
    }
}

// 2 big input mats (F x H) -> w0comb rows [0,256) lin, [256,512) gc
__global__ __launch_bounds__(256) void transpose_cast_in(
    const float* __restrict__ Wl, const float* __restrict__ Wg,
    _Float16* __restrict__ dst, int K, int N)
{
    const float* W = blockIdx.z ? Wg : Wl;
    _Float16* D = dst + (size_t)blockIdx.z * N * K;
    tc_tile(W, D, K, N, blockIdx.x * 32, blockIdx.y * 32,
            threadIdx.x & 31, threadIdx.x >> 5);
}

// 6 hidden mats (256x256): z=2l+j, j=0 lins -> wl, j=1 convs -> wl+H*H
__global__ __launch_bounds__(256) void transpose_cast_hid(
    const float* __restrict__ lins, const float* __restrict__ convs,
    _Float16* __restrict__ wcomb)
{
    const int l = blockIdx.z >> 1, j = blockIdx.z & 1;
    const float* W = (j ? convs : lins) + (size_t)l * 256 * 256;
    _Float16* D = wcomb + (size_t)l * 512 * 256 + (size_t)j * 256 * 256;
    tc_tile(W, D, 256, 256, blockIdx.x * 32, blockIdx.y * 32,
            threadIdx.x & 31, threadIdx.x >> 5);
}

__global__ __launch_bounds__(256) void transpose_cast_one(
    const float* __restrict__ W, _Float16* __restrict__ WT, int K, int N)
{
    tc_tile(W, WT, K, N, blockIdx.x * 32, blockIdx.y * 32,
            threadIdx.x & 31, threadIdx.x >> 5);
}

// ---------------- scan for CSR (also emits dinv) ----------------
__global__ __launch_bounds__(256) void scan_block(const int* __restrict__ count,
                                                  int* __restrict__ incl,
                                                  int* __restrict__ blocksum,
                                                  float* __restrict__ dinv, int n) {
    __shared__ int tmp[256];
    int t = threadIdx.x;
    int i = blockIdx.x * 256 + t;
    int v = (i < n) ? count[i] : 0;
    if (i < n) dinv[i] = rsqrtf(1.0f + (float)v);
    tmp[t] = v;
    __syncthreads();
    for (int off = 1; off < 256; off <<= 1) {
        int x = (t >= off) ? tmp[t - off] : 0;
        __syncthreads();
        tmp[t] += x;
        __syncthreads();
    }
    if (i < n) incl[i] = tmp[t];
    if (t == 255) blocksum[blockIdx.x] = tmp[255];
}

__global__ __launch_bounds__(256) void scan_top(const int* __restrict__ blocksum,
                                                int* __restrict__ blockoff, int nb) {
    __shared__ int tmp[256];
    int t = threadIdx.x;
    int v = (t < nb) ? blocksum[t] : 0;
    tmp[t] = v;
    __syncthreads();
    for (int off = 1; off < 256; off <<= 1) {
        int x = (t >= off) ? tmp[t - off] : 0;
        __syncthreads();
        tmp[t] += x;
        __syncthreads();
    }
    if (t < nb) blockoff[t] = tmp[t] - v;
}

__global__ __launch_bounds__(256) void make_rowptr(const int* __restrict__ incl,
                                                   const int* __restrict__ count,
                                                   const int* __restrict__ blockoff,
                                                   int* __restrict__ rowptr,
                                                   int* __restrict__ cursor, int n) {
    int i = blockIdx.x * 256 + threadIdx.x;
    if (i < n) {
        int r = incl[i] - count[i] + blockoff[blockIdx.x];
        rowptr[i] = r;
        cursor[i] = r;
    }
}

__global__ __launch_bounds__(256) void scatter_perm(const int* __restrict__ src,
                                                    const int* __restrict__ dst,
                                                    const float* __restrict__ dinv,
                                                    int* __restrict__ cursor,
                                                    int2* __restrict__ sorted_meta, int E) {
    int e = blockIdx.x * 256 + threadIdx.x;
    if (e < E) {
        int d = dst[e], s = src[e];
        int slot = atomicAdd(&cursor[d], 1);
        sorted_meta[slot] = make_int2(s, __float_as_int(dinv[s] * dinv[d]));
    }
}

// ---------------- dual fp16 MFMA GEMM: LDS/gld16 staging + XCD m-swizzle ----
// C[M x 512] = A[M x K](lda) @ BT[512 x K]^T; tile 128x128, 4 waves 2x2.
// blockIdx%8 == m_t%8: all 4 n-tiles of an m-tile land on one XCD -> A-tile
// fetched into exactly one L2. cols<256 -> lin_h (+biases), >=256 -> hw.
__global__ __launch_bounds__(256) void gemm_dual(
    const _Float16* __restrict__ A, int lda,
    const _Float16* __restrict__ BT, int K,
    const float* __restrict__ bias0, const float* __restrict__ bias1,
    _Float16* __restrict__ lin_h, _Float16* __restrict__ hw,
    int M, int m_tiles)
{
    const int b     = blockIdx.x;
    const int x     = b & 7;
    const int inner = b >> 3;
    const int n_t   = inner & 3;
    const int m_t   = (inner >> 2) * 8 + x;
    if (m_t >= m_tiles) return;
    const int bm = m_t * 128, bn = n_t * 128;

    __shared__ _Float16 As[128 * 64];
    __shared__ _Float16 Bs[128 * 64];

    const int wave = threadIdx.x >> 6, lane = threadIdx.x & 63;
    const int q = lane >> 4, r = lane & 15;
    const int wm = (wave & 1) * 64, wn = (wave >> 1) * 64;
    const int srow = wave * 32, lrow8 = lane >> 3, cp = lane & 7;

    floatx4 acc[4][4] = {};

    for (int k0 = 0; k0 < K; k0 += 64) {
        #pragma unroll
        for (int t = 0; t < 4; ++t) {
            int lrow = srow + t * 8 + lrow8;
            int c    = cp ^ (lrow & 7);
            int gm = bm + lrow; if (gm > M - 1) gm = M - 1;
            gld16(&A[(size_t)gm * lda + k0 + c * 8], &As[(srow + t * 8) * 64]);
            int gn = bn + lrow;   // always < 512
            gld16(&BT[(size_t)gn * K + k0 + c * 8], &Bs[(srow + t * 8) * 64]);
        }
        __syncthreads();

        #pragma unroll
        for (int kk = 0; kk < 2; ++kk) {
            const int sc = ((kk << 2) | q) ^ (r & 7);
            half8 af[4], bf[4];
            #pragma unroll
            for (int mi = 0; mi < 4; ++mi)
                af[mi] = *(const half8*)&As[(wm + mi * 16 + r) * 64 + sc * 8];
            #pragma unroll
            for (int ni = 0; ni < 4; ++ni)
                bf[ni] = *(const half8*)&Bs[(wn + ni * 16 + r) * 64 + sc * 8];
            #pragma unroll
            for (int mi = 0; mi < 4; ++mi)
                #pragma unroll
                for (int ni = 0; ni < 4; ++ni)
                    acc[mi][ni] = __builtin_amdgcn_mfma_f32_16x16x32_f16(
                        af[mi], bf[ni], acc[mi][ni], 0, 0, 0);
        }
        __syncthreads();
    }

    // epilogue, ni-innermost (4 consecutive stores span a 128B row segment)
    const bool islin = (bn < 256);
    _Float16* dstp = islin ? lin_h : hw;
    const int cbase = (islin ? bn : bn - 256) + wn;
    float badd[4];
    #pragma unroll
    for (int ni = 0; ni < 4; ++ni) {
        int col = bn + wn + ni * 16 + r;
        badd[ni] = islin ? (bias0[col] + bias1[col]) : 0.0f;
    }
    #pragma unroll
    for (int mi = 0; mi < 4; ++mi)
        #pragma unroll
        for (int reg = 0; reg < 4; ++reg) {
            int gm = bm + wm + mi * 16 + q * 4 + reg;
            if (gm >= M) continue;
            #pragma unroll
            for (int ni = 0; ni < 4; ++ni)
                dstp[(size_t)gm * 256 + cbase + ni * 16 + r] =
                    (_Float16)(acc[mi][ni][reg] + badd[ni]);
        }
}

// ---------------- out GEMM: 256x64 tile, 4 waves stacked on m ----------------
// out[M x 40] = jk[M x 1024] @ outWT[40 x 1024]^T + bias. No dead waves.
__global__ __launch_bounds__(256) void gemm_out(
    const _Float16* __restrict__ A,      // lda = 1024
    const _Float16* __restrict__ BT,     // 40 x 1024
    const float* __restrict__ bias,
    float* __restrict__ Cf, int M)
{
    const int bm = blockIdx.x * 256;
    __shared__ _Float16 As[256 * 64];    // 32 KB
    __shared__ _Float16 Bs[64 * 64];     // 8 KB

    const int wave = threadIdx.x >> 6, lane = threadIdx.x & 63;
    const int q = lane >> 4, r = lane & 15;
    const int wm = wave * 64;
    const int lrow8 = lane >> 3, cp = lane & 7;

    floatx4 acc[4][4] = {};

    for (int k0 = 0; k0 < 1024; k0 += 64) {
        #pragma unroll
        for (int t = 0; t < 8; ++t) {
            int lrow = wm + t * 8 + lrow8;
            int c    = cp ^ (lrow & 7);
            int gm = bm + lrow; if (gm > M - 1) gm = M - 1;
            gld16(&A[(size_t)gm * 1024 + k0 + c * 8], &As[(wm + t * 8) * 64]);
        }
        #pragma unroll
        for (int t = 0; t < 2; ++t) {
            int brow = wave * 16 + t * 8 + lrow8;
            int c    = cp ^ (brow & 7);
            int gn = brow; if (gn > 39) gn = 39;
            gld16(&BT[(size_t)gn * 1024 + k0 + c * 8], &Bs[(wave * 16 + t * 8) * 64]);
        }
        __syncthreads();

        #pragma unroll
        for (int kk = 0; kk < 2; ++kk) {
            const int sc = ((kk << 2) | q) ^ (r & 7);
            half8 af[4], bf[4];
            #pragma unroll
            for (int mi = 0; mi < 4; ++mi)
                af[mi] = *(const half8*)&As[(wm + mi * 16 + r) * 64 + sc * 8];
            #pragma unroll
            for (int ni = 0; ni < 4; ++ni)
                bf[ni] = *(const half8*)&Bs[(ni * 16 + r) * 64 + sc * 8];
            #pragma unroll
            for (int mi = 0; mi < 4; ++mi)
                #pragma unroll
                for (int ni = 0; ni < 4; ++ni)
                    acc[mi][ni] = __builtin_amdgcn_mfma_f32_16x16x32_f16(
                        af[mi], bf[ni], acc[mi][ni], 0, 0, 0);
        }
        __syncthreads();
    }

    float badd[4];
    #pragma unroll
    for (int ni = 0; ni < 4; ++ni) {
        int col = ni * 16 + r;
        badd[ni] = (col < 40) ? bias[col] : 0.0f;
    }
    #pragma unroll
    for (int mi = 0; mi < 4; ++mi)
        #pragma unroll
        for (int reg = 0; reg < 4; ++reg) {
            int gm = bm + wm + mi * 16 + q * 4 + reg;
            if (gm >= M) continue;
            #pragma unroll
            for (int ni = 0; ni < 4; ++ni) {
                int col = ni * 16 + r;
                if (col < 40)
                    Cf[(size_t)gm * 40 + col] = acc[mi][ni][reg] + badd[ni];
            }
        }
}

// ---------------- fused CSR aggregate, feature-split across XCDs ----------------
// quarter-wave (16 lanes x half8 = 256B) per edge; meta read directly
// (same 8B address across the 16 lanes -> 1 line, no shfl chain);
// 8-deep unroll = 8 gathers (2 KB) in flight per wave.
__global__ __launch_bounds__(256) void aggregate_csr(
    const int* __restrict__ rowptr, const int* __restrict__ count,
    const int2* __restrict__ sorted_meta,
    const float* __restrict__ dinv,
    const _Float16* __restrict__ hw,
    const _Float16* __restrict__ lin_h,
    _Float16* __restrict__ jk_col, int n)
{
    const int bx    = blockIdx.x;
    const int xslot = bx & 7;
    const int half  = xslot >> 2;
    const int chunk = ((bx >> 3) << 2) + (xslot & 3);
    const int wave  = threadIdx.x >> 6;
    const int lane  = threadIdx.x & 63;
    const int i     = chunk * 4 + wave;
    if (i >= n) return;

    const int qw = lane >> 4;
    const int fl = lane & 15;
    const int fbase = half * 128 + fl * 8;

    const int start = rowptr[i];
    const int deg   = count[i];

    float accf[8] = {};
    if (qw == 0) {
        half8 l8 = *(const half8*)&lin_h[(size_t)i * 256 + fbase];
        #pragma unroll
        for (int t = 0; t < 8; ++t) accf[t] = (float)l8[t];
    } else if (qw == 1) {
        float di = dinv[i];
        float sn = di * di;
        half8 s8 = *(const half8*)&hw[(size_t)i * 256 + fbase];
        #pragma unroll
        for (int t = 0; t < 8; ++t) accf[t] = (float)s8[t] * sn;
    }

    const int2* mp = sorted_meta + start;
    for (int j = 0; j < deg; j += 32) {
        half8 hv[8];
        float nm[8];
        #pragma unroll
        for (int k2 = 0; k2 < 8; ++k2) {
            int e  = j + k2 * 4 + qw;
            int ec = (e < deg) ? e : (deg - 1);
            int2 mt = mp[ec];
            nm[k2] = (e < deg) ? __int_as_float(mt.y) : 0.0f;
            hv[k2] = *(const half8*)&hw[(size_t)mt.x * 256 + fbase];
        }
        #pragma unroll
        for (int k2 = 0; k2 < 8; ++k2)
            #pragma unroll
            for (int t = 0; t < 8; ++t)
                accf[t] = fmaf((float)hv[k2][t], nm[k2], accf[t]);
    }

    #pragma unroll
    for (int t = 0; t < 8; ++t) {
        accf[t] += __shfl_xor(accf[t], 16, 64);
        accf[t] += __shfl_xor(accf[t], 32, 64);
    }

    if (qw == 0) {
        half8 o;
        #pragma unroll
        for (int t = 0; t < 8; ++t) o[t] = (_Float16)fmaxf(accf[t], 0.0f);
        *(half8*)&jk_col[(size_t)i * 1024 + fbase] = o;
    }
}

extern "C" void kernel_launch(void* const* d_in, const int* in_sizes, int n_in,
                              void* d_out, int out_size, void* d_ws, size_t ws_size,
                              hipStream_t stream) {
    const float* x        = (const float*)d_in[0];
    const int*   ei       = (const int*)d_in[1];
    const float* in_gc_W  = (const float*)d_in[2];
    const float* in_gc_b  = (const float*)d_in[3];
    const float* in_lin_W = (const float*)d_in[4];
    const float* in_lin_b = (const float*)d_in[5];
    const float* convs_W  = (const float*)d_in[6];
    const float* convs_b  = (const float*)d_in[7];
    const float* lins_W   = (const float*)d_in[8];
    const float* lins_b   = (const float*)d_in[9];
    const float* out_W    = (const float*)d_in[10];
    const float* out_b    = (const float*)d_in[11];

    const int N = 50000;
    const int E = in_sizes[1] / 2;
    const int F = 512, H = 256, L = 4, NC = 40;

    const int* src = ei;
    const int* dst = ei + E;

    char* ws = (char*)d_ws;
    auto carve = [&](size_t bytes) { void* p = ws; ws += (bytes + 255) & ~(size_t)255; return p; };
    float*    dinv        = (float*)carve((size_t)N * 4);
    int*      count       = (int*)  carve((size_t)N * 4);
    int*      incl        = (int*)  carve((size_t)N * 4);
    int*      rowptr      = (int*)  carve((size_t)N * 4);
    int*      cursor      = (int*)  carve((size_t)N * 4);
    int*      blocksum    = (int*)  carve(256 * 4);
    int*      blockoff    = (int*)  carve(256 * 4);
    int2*     sorted_meta = (int2*) carve((size_t)E * 8);
    _Float16* xh          = (_Float16*)carve((size_t)N * F * 2);
    _Float16* w0comb      = (_Float16*)carve((size_t)512 * F * 2);
    _Float16* wcomb       = (_Float16*)carve((size_t)3 * 512 * H * 2);
    _Float16* outWT       = (_Float16*)carve((size_t)NC * H * L * 2);
    _Float16* lin_h       = (_Float16*)carve((size_t)N * H * 2);
    _Float16* hw          = (_Float16*)carve((size_t)N * H * 2);
    _Float16* jk_h        = (_Float16*)carve((size_t)N * H * L * 2);
    float*    out         = (float*)d_out;

    const int nbN = (N + 255) / 256;
    const int nbE = (E + 255) / 256;

    // 1) x-cast (+count zeroing), CSR build
    cast_x_zero<<<(N * F / 8 + 255) / 256, 256, 0, stream>>>(x, xh, N * F / 8, count, N);
    hist_dst<<<nbE, 256, 0, stream>>>(dst, count, E);
    scan_block<<<nbN, 256, 0, stream>>>(count, incl, blocksum, dinv, N);
    scan_top<<<1, 256, 0, stream>>>(blocksum, blockoff, nbN);
    make_rowptr<<<nbN, 256, 0, stream>>>(incl, count, blockoff, rowptr, cursor, N);
    scatter_perm<<<nbE, 256, 0, stream>>>(src, dst, dinv, cursor, sorted_meta, E);

    // 2) batched weight transposes (3 launches)
    transpose_cast_in<<<dim3(F / 32, H / 32, 2), 256, 0, stream>>>(in_lin_W, in_gc_W, w0comb, F, H);
    transpose_cast_hid<<<dim3(H / 32, H / 32, 6), 256, 0, stream>>>(lins_W, convs_W, wcomb);
    transpose_cast_one<<<dim3(H * L / 32, (NC + 31) / 32), 256, 0, stream>>>(out_W, outWT, H * L, NC);

    const int m_tiles = (N + 127) / 128;                  // 391
    const int dual_blocks = 8 * ((m_tiles + 7) / 8) * 4;  // 1568
    const int agg_blocks  = 2 * ((N + 3) / 4);            // 25000
    const int out_blocks  = (N + 255) / 256;              // 196

    // 3) layers
    for (int l = 0; l < L; ++l) {
        const _Float16* Ah = (l == 0) ? xh : (jk_h + (size_t)(l - 1) * H);
        int lda            = (l == 0) ? F : H * L;
        int K              = (l == 0) ? F : H;
        const _Float16* BT = (l == 0) ? w0comb : (wcomb + (size_t)(l - 1) * 512 * H);
        const float* gcB   = (l == 0) ? in_gc_b  : (convs_b + (size_t)(l - 1) * H);
        const float* liB   = (l == 0) ? in_lin_b : (lins_b  + (size_t)(l - 1) * H);

        gemm_dual<<<dual_blocks, 256, 0, stream>>>(Ah, lda, BT, K, liB, gcB,
                                                   lin_h, hw, N, m_tiles);
        aggregate_csr<<<agg_blocks, 256, 0, stream>>>(rowptr, count, sorted_meta,
                                                      dinv, hw, lin_h, jk_h + (size_t)l * H, N);
    }

    // 4) out = jk_h @ out_W + out_b
    gemm_out<<<out_blocks, 256, 0, stream>>>(jk_h, outWT, out_b, out, N);
}

// Round 9
// 753.258 us; speedup vs baseline: 1.1363x; 1.0845x over previous
//
#include <hip/hip_runtime.h>

typedef _Float16 half8 __attribute__((ext_vector_type(8)));
typedef _Float16 half4 __attribute__((ext_vector_type(4)));
typedef float floatx4 __attribute__((ext_vector_type(4)));

// async global->LDS, 16B per lane. LDS dest is wave-uniform base + lane*16.
__device__ __forceinline__ void gld16(const _Float16* g, _Float16* lds_base) {
    __builtin_amdgcn_global_load_lds(
        (const __attribute__((address_space(1))) unsigned int*)g,
        (__attribute__((address_space(3))) unsigned int*)lds_base,
        16, 0, 0);
}

// ---------------- fused x-cast (fp32->fp16, 16B stores) + count zeroing ----
__global__ __launch_bounds__(256) void cast_x_zero(const float* __restrict__ in,
                                                   _Float16* __restrict__ out, int n8,
                                                   int* __restrict__ count, int nzero) {
    int i = blockIdx.x * 256 + threadIdx.x;
    if (i < n8) {
        float4 v0 = *(const float4*)&in[(size_t)i * 8];
        float4 v1 = *(const float4*)&in[(size_t)i * 8 + 4];
        half8 h = { (_Float16)v0.x, (_Float16)v0.y, (_Float16)v0.z, (_Float16)v0.w,
                    (_Float16)v1.x, (_Float16)v1.y, (_Float16)v1.z, (_Float16)v1.w };
        *(half8*)&out[(size_t)i * 8] = h;
    }
    if (i < nzero) count[i] = 0;
}

__global__ __launch_bounds__(256) void hist_dst(const int* __restrict__ dst,
                                                int* __restrict__ count, int E) {
    int e = blockIdx.x * 256 + threadIdx.x;
    if (e < E) atomicAdd(&count[dst[e]], 1);
}

// ---------------- batched tiled transpose+cast kernels ----------------
__device__ __forceinline__ void tc_tile(const float* W, _Float16* WT, int K, int N,
                                        int k0, int n0, int tx, int ty) {
    __shared__ _Float16 t[32][33];
    #pragma unroll
    for (int i = 0; i < 4; ++i) {
        int k = k0 + ty + i * 8, n = n0 + tx;
        float v = (k < K && n < N) ? W[(size_t)k * N + n] : 0.0f;
        t[ty + i * 8][tx] = (_Float16)v;
    }
    __syncthreads();
    #pragma unroll
    for (int i = 0; i < 4; ++i) {
        int n = n0 + ty + i * 8, k = k0 + tx;
        if (n < N && k < K) WT[(size_t)n * K + k] = t[tx][ty + i * 8];
    }
}

__global__ __launch_bounds__(256) void transpose_cast_in(
    const float* __restrict__ Wl, const float* __restrict__ Wg,
    _Float16* __restrict__ dst, int K, int N)
{
    const float* W = blockIdx.z ? Wg : Wl;
    _Float16* D = dst + (size_t)blockIdx.z * N * K;
    tc_tile(W, D, K, N, blockIdx.x * 32, blockIdx.y * 32,
            threadIdx.x & 31, threadIdx.x >> 5);
}

__global__ __launch_bounds__(256) void transpose_cast_hid(
    const float* __restrict__ lins, const float* __restrict__ convs,
    _Float16* __restrict__ wcomb)
{
    const int l = blockIdx.z >> 1, j = blockIdx.z & 1;
    const float* W = (j ? convs : lins) + (size_t)l * 256 * 256;
    _Float16* D = wcomb + (size_t)l * 512 * 256 + (size_t)j * 256 * 256;
    tc_tile(W, D, 256, 256, blockIdx.x * 32, blockIdx.y * 32,
            threadIdx.x & 31, threadIdx.x >> 5);
}

__global__ __launch_bounds__(256) void transpose_cast_one(
    const float* __restrict__ W, _Float16* __restrict__ WT, int K, int N)
{
    tc_tile(W, WT, K, N, blockIdx.x * 32, blockIdx.y * 32,
            threadIdx.x & 31, threadIdx.x >> 5);
}

// ---------------- scan for CSR (also emits dinv) ----------------
__global__ __launch_bounds__(256) void scan_block(const int* __restrict__ count,
                                                  int* __restrict__ incl,
                                                  int* __restrict__ blocksum,
                                                  float* __restrict__ dinv, int n) {
    __shared__ int tmp[256];
    int t = threadIdx.x;
    int i = blockIdx.x * 256 + t;
    int v = (i < n) ? count[i] : 0;
    if (i < n) dinv[i] = rsqrtf(1.0f + (float)v);
    tmp[t] = v;
    __syncthreads();
    for (int off = 1; off < 256; off <<= 1) {
        int x = (t >= off) ? tmp[t - off] : 0;
        __syncthreads();
        tmp[t] += x;
        __syncthreads();
    }
    if (i < n) incl[i] = tmp[t];
    if (t == 255) blocksum[blockIdx.x] = tmp[255];
}

__global__ __launch_bounds__(256) void scan_top(const int* __restrict__ blocksum,
                                                int* __restrict__ blockoff, int nb) {
    __shared__ int tmp[256];
    int t = threadIdx.x;
    int v = (t < nb) ? blocksum[t] : 0;
    tmp[t] = v;
    __syncthreads();
    for (int off = 1; off < 256; off <<= 1) {
        int x = (t >= off) ? tmp[t - off] : 0;
        __syncthreads();
        tmp[t] += x;
        __syncthreads();
    }
    if (t < nb) blockoff[t] = tmp[t] - v;
}

__global__ __launch_bounds__(256) void make_rowptr(const int* __restrict__ incl,
                                                   const int* __restrict__ count,
                                                   const int* __restrict__ blockoff,
                                                   int* __restrict__ rowptr,
                                                   int* __restrict__ cursor, int n) {
    int i = blockIdx.x * 256 + threadIdx.x;
    if (i < n) {
        int r = incl[i] - count[i] + blockoff[blockIdx.x];
        rowptr[i] = r;
        cursor[i] = r;
    }
}

__global__ __launch_bounds__(256) void scatter_perm(const int* __restrict__ src,
                                                    const int* __restrict__ dst,
                                                    const float* __restrict__ dinv,
                                                    int* __restrict__ cursor,
                                                    int2* __restrict__ sorted_meta, int E) {
    int e = blockIdx.x * 256 + threadIdx.x;
    if (e < E) {
        int d = dst[e], s = src[e];
        int slot = atomicAdd(&cursor[d], 1);
        sorted_meta[slot] = make_int2(s, __float_as_int(dinv[s] * dinv[d]));
    }
}

// ---------------- dual fp16 MFMA GEMM: LDS/gld16 staging + XCD m-swizzle ----
__global__ __launch_bounds__(256) void gemm_dual(
    const _Float16* __restrict__ A, int lda,
    const _Float16* __restrict__ BT, int K,
    const float* __restrict__ bias0, const float* __restrict__ bias1,
    _Float16* __restrict__ lin_h, _Float16* __restrict__ hw,
    int M, int m_tiles)
{
    const int b     = blockIdx.x;
    const int x     = b & 7;
    const int inner = b >> 3;
    const int n_t   = inner & 3;
    const int m_t   = (inner >> 2) * 8 + x;
    if (m_t >= m_tiles) return;
    const int bm = m_t * 128, bn = n_t * 128;

    __shared__ _Float16 As[128 * 64];
    __shared__ _Float16 Bs[128 * 64];

    const int wave = threadIdx.x >> 6, lane = threadIdx.x & 63;
    const int q = lane >> 4, r = lane & 15;
    const int wm = (wave & 1) * 64, wn = (wave >> 1) * 64;
    const int srow = wave * 32, lrow8 = lane >> 3, cp = lane & 7;

    floatx4 acc[4][4] = {};

    for (int k0 = 0; k0 < K; k0 += 64) {
        #pragma unroll
        for (int t = 0; t < 4; ++t) {
            int lrow = srow + t * 8 + lrow8;
            int c    = cp ^ (lrow & 7);
            int gm = bm + lrow; if (gm > M - 1) gm = M - 1;
            gld16(&A[(size_t)gm * lda + k0 + c * 8], &As[(srow + t * 8) * 64]);
            int gn = bn + lrow;   // always < 512
            gld16(&BT[(size_t)gn * K + k0 + c * 8], &Bs[(srow + t * 8) * 64]);
        }
        __syncthreads();

        #pragma unroll
        for (int kk = 0; kk < 2; ++kk) {
            const int sc = ((kk << 2) | q) ^ (r & 7);
            half8 af[4], bf[4];
            #pragma unroll
            for (int mi = 0; mi < 4; ++mi)
                af[mi] = *(const half8*)&As[(wm + mi * 16 + r) * 64 + sc * 8];
            #pragma unroll
            for (int ni = 0; ni < 4; ++ni)
                bf[ni] = *(const half8*)&Bs[(wn + ni * 16 + r) * 64 + sc * 8];
            #pragma unroll
            for (int mi = 0; mi < 4; ++mi)
                #pragma unroll
                for (int ni = 0; ni < 4; ++ni)
                    acc[mi][ni] = __builtin_amdgcn_mfma_f32_16x16x32_f16(
                        af[mi], bf[ni], acc[mi][ni], 0, 0, 0);
        }
        __syncthreads();
    }

    const bool islin = (bn < 256);
    _Float16* dstp = islin ? lin_h : hw;
    const int cbase = (islin ? bn : bn - 256) + wn;
    float badd[4];
    #pragma unroll
    for (int ni = 0; ni < 4; ++ni) {
        int col = bn + wn + ni * 16 + r;
        badd[ni] = islin ? (bias0[col] + bias1[col]) : 0.0f;
    }
    #pragma unroll
    for (int mi = 0; mi < 4; ++mi)
        #pragma unroll
        for (int reg = 0; reg < 4; ++reg) {
            int gm = bm + wm + mi * 16 + q * 4 + reg;
            if (gm >= M) continue;
            #pragma unroll
            for (int ni = 0; ni < 4; ++ni)
                dstp[(size_t)gm * 256 + cbase + ni * 16 + r] =
                    (_Float16)(acc[mi][ni][reg] + badd[ni]);
        }
}

// ---------------- out GEMM: 256x64 tile, 4 waves stacked on m ----------------
__global__ __launch_bounds__(256) void gemm_out(
    const _Float16* __restrict__ A,      // lda = 1024
    const _Float16* __restrict__ BT,     // 40 x 1024
    const float* __restrict__ bias,
    float* __restrict__ Cf, int M)
{
    const int bm = blockIdx.x * 256;
    __shared__ _Float16 As[256 * 64];
    __shared__ _Float16 Bs[64 * 64];

    const int wave = threadIdx.x >> 6, lane = threadIdx.x & 63;
    const int q = lane >> 4, r = lane & 15;
    const int wm = wave * 64;
    const int lrow8 = lane >> 3, cp = lane & 7;

    floatx4 acc[4][4] = {};

    for (int k0 = 0; k0 < 1024; k0 += 64) {
        #pragma unroll
        for (int t = 0; t < 8; ++t) {
            int lrow = wm + t * 8 + lrow8;
            int c    = cp ^ (lrow & 7);
            int gm = bm + lrow; if (gm > M - 1) gm = M - 1;
            gld16(&A[(size_t)gm * 1024 + k0 + c * 8], &As[(wm + t * 8) * 64]);
        }
        #pragma unroll
        for (int t = 0; t < 2; ++t) {
            int brow = wave * 16 + t * 8 + lrow8;
            int c    = cp ^ (brow & 7);
            int gn = brow; if (gn > 39) gn = 39;
            gld16(&BT[(size_t)gn * 1024 + k0 + c * 8], &Bs[(wave * 16 + t * 8) * 64]);
        }
        __syncthreads();

        #pragma unroll
        for (int kk = 0; kk < 2; ++kk) {
            const int sc = ((kk << 2) | q) ^ (r & 7);
            half8 af[4], bf[4];
            #pragma unroll
            for (int mi = 0; mi < 4; ++mi)
                af[mi] = *(const half8*)&As[(wm + mi * 16 + r) * 64 + sc * 8];
            #pragma unroll
            for (int ni = 0; ni < 4; ++ni)
                bf[ni] = *(const half8*)&Bs[(ni * 16 + r) * 64 + sc * 8];
            #pragma unroll
            for (int mi = 0; mi < 4; ++mi)
                #pragma unroll
                for (int ni = 0; ni < 4; ++ni)
                    acc[mi][ni] = __builtin_amdgcn_mfma_f32_16x16x32_f16(
                        af[mi], bf[ni], acc[mi][ni], 0, 0, 0);
        }
        __syncthreads();
    }

    float badd[4];
    #pragma unroll
    for (int ni = 0; ni < 4; ++ni) {
        int col = ni * 16 + r;
        badd[ni] = (col < 40) ? bias[col] : 0.0f;
    }
    #pragma unroll
    for (int mi = 0; mi < 4; ++mi)
        #pragma unroll
        for (int reg = 0; reg < 4; ++reg) {
            int gm = bm + wm + mi * 16 + q * 4 + reg;
            if (gm >= M) continue;
            #pragma unroll
            for (int ni = 0; ni < 4; ++ni) {
                int col = ni * 16 + r;
                if (col < 40)
                    Cf[(size_t)gm * 40 + col] = acc[mi][ni][reg] + badd[ni];
            }
        }
}

// ---------------- fused CSR aggregate, feature-split across XCDs ----------------
// R6-proven scheme: coalesced meta load (8B/lane per 64 edges) + shfl broadcast;
// quarter-wave (16 lanes x half8 = 256B) per edge; deepened to 8 gathers/lane.
__global__ __launch_bounds__(256) void aggregate_csr(
    const int* __restrict__ rowptr, const int* __restrict__ count,
    const int2* __restrict__ sorted_meta,
    const float* __restrict__ dinv,
    const _Float16* __restrict__ hw,
    const _Float16* __restrict__ lin_h,
    _Float16* __restrict__ jk_col, int n)
{
    const int bx    = blockIdx.x;
    const int xslot = bx & 7;
    const int half  = xslot >> 2;
    const int chunk = ((bx >> 3) << 2) + (xslot & 3);
    const int wave  = threadIdx.x >> 6;
    const int lane  = threadIdx.x & 63;
    const int i     = chunk * 4 + wave;
    if (i >= n) return;

    const int qw = lane >> 4;
    const int fl = lane & 15;
    const int fbase = half * 128 + fl * 8;

    const int start = rowptr[i];
    const int deg   = count[i];

    float accf[8] = {};
    if (qw == 0) {
        half8 l8 = *(const half8*)&lin_h[(size_t)i * 256 + fbase];
        #pragma unroll
        for (int t = 0; t < 8; ++t) accf[t] = (float)l8[t];
    } else if (qw == 1) {
        float di = dinv[i];
        float sn = di * di;
        half8 s8 = *(const half8*)&hw[(size_t)i * 256 + fbase];
        #pragma unroll
        for (int t = 0; t < 8; ++t) accf[t] = (float)s8[t] * sn;
    }

    for (int base = 0; base < deg; base += 64) {
        int m = deg - base;
        if (m > 64) m = 64;
        int2 meta = make_int2(0, 0);
        if (lane < m) meta = sorted_meta[start + base + lane];

        for (int j = 0; j < m; j += 32) {
            half8 hv[8];
            float nm[8];
            #pragma unroll
            for (int k2 = 0; k2 < 8; ++k2) {
                int e   = j + k2 * 4 + qw;
                int idx = (e < m) ? e : (m - 1);
                int s   = __shfl(meta.x, idx, 64);
                int nmb = __shfl(meta.y, idx, 64);
                nm[k2]  = (e < m) ? __int_as_float(nmb) : 0.0f;
                hv[k2]  = *(const half8*)&hw[(size_t)s * 256 + fbase];
            }
            #pragma unroll
            for (int k2 = 0; k2 < 8; ++k2)
                #pragma unroll
                for (int t = 0; t < 8; ++t)
                    accf[t] = fmaf((float)hv[k2][t], nm[k2], accf[t]);
        }
    }

    #pragma unroll
    for (int t = 0; t < 8; ++t) {
        accf[t] += __shfl_xor(accf[t], 16, 64);
        accf[t] += __shfl_xor(accf[t], 32, 64);
    }

    if (qw == 0) {
        half8 o;
        #pragma unroll
        for (int t = 0; t < 8; ++t) o[t] = (_Float16)fmaxf(accf[t], 0.0f);
        *(half8*)&jk_col[(size_t)i * 1024 + fbase] = o;
    }
}

extern "C" void kernel_launch(void* const* d_in, const int* in_sizes, int n_in,
                              void* d_out, int out_size, void* d_ws, size_t ws_size,
                              hipStream_t stream) {
    const float* x        = (const float*)d_in[0];
    const int*   ei       = (const int*)d_in[1];
    const float* in_gc_W  = (const float*)d_in[2];
    const float* in_gc_b  = (const float*)d_in[3];
    const float* in_lin_W = (const float*)d_in[4];
    const float* in_lin_b = (const float*)d_in[5];
    const float* convs_W  = (const float*)d_in[6];
    const float* convs_b  = (const float*)d_in[7];
    const float* lins_W   = (const float*)d_in[8];
    const float* lins_b   = (const float*)d_in[9];
    const float* out_W    = (const float*)d_in[10];
    const float* out_b    = (const float*)d_in[11];

    const int N = 50000;
    const int E = in_sizes[1] / 2;
    const int F = 512, H = 256, L = 4, NC = 40;

    const int* src = ei;
    const int* dst = ei + E;

    char* ws = (char*)d_ws;
    auto carve = [&](size_t bytes) { void* p = ws; ws += (bytes + 255) & ~(size_t)255; return p; };
    float*    dinv        = (float*)carve((size_t)N * 4);
    int*      count       = (int*)  carve((size_t)N * 4);
    int*      incl        = (int*)  carve((size_t)N * 4);
    int*      rowptr      = (int*)  carve((size_t)N * 4);
    int*      cursor      = (int*)  carve((size_t)N * 4);
    int*      blocksum    = (int*)  carve(256 * 4);
    int*      blockoff    = (int*)  carve(256 * 4);
    int2*     sorted_meta = (int2*) carve((size_t)E * 8);
    _Float16* xh          = (_Float16*)carve((size_t)N * F * 2);
    _Float16* w0comb      = (_Float16*)carve((size_t)512 * F * 2);
    _Float16* wcomb       = (_Float16*)carve((size_t)3 * 512 * H * 2);
    _Float16* outWT       = (_Float16*)carve((size_t)NC * H * L * 2);
    _Float16* lin_h       = (_Float16*)carve((size_t)N * H * 2);
    _Float16* hw          = (_Float16*)carve((size_t)N * H * 2);
    _Float16* jk_h        = (_Float16*)carve((size_t)N * H * L * 2);
    float*    out         = (float*)d_out;

    const int nbN = (N + 255) / 256;
    const int nbE = (E + 255) / 256;

    // 1) x-cast (+count zeroing), CSR build
    cast_x_zero<<<(N * F / 8 + 255) / 256, 256, 0, stream>>>(x, xh, N * F / 8, count, N);
    hist_dst<<<nbE, 256, 0, stream>>>(dst, count, E);
    scan_block<<<nbN, 256, 0, stream>>>(count, incl, blocksum, dinv, N);
    scan_top<<<1, 256, 0, stream>>>(blocksum, blockoff, nbN);
    make_rowptr<<<nbN, 256, 0, stream>>>(incl, count, blockoff, rowptr, cursor, N);
    scatter_perm<<<nbE, 256, 0, stream>>>(src, dst, dinv, cursor, sorted_meta, E);

    // 2) batched weight transposes (3 launches)
    transpose_cast_in<<<dim3(F / 32, H / 32, 2), 256, 0, stream>>>(in_lin_W, in_gc_W, w0comb, F, H);
    transpose_cast_hid<<<dim3(H / 32, H / 32, 6), 256, 0, stream>>>(lins_W, convs_W, wcomb);
    transpose_cast_one<<<dim3(H * L / 32, (NC + 31) / 32), 256, 0, stream>>>(out_W, outWT, H * L, NC);

    const int m_tiles = (N + 127) / 128;                  // 391
    const int dual_blocks = 8 * ((m_tiles + 7) / 8) * 4;  // 1568
    const int agg_blocks  = 2 * ((N + 3) / 4);            // 25000
    const int out_blocks  = (N + 255) / 256;              // 196

    // 3) layers
    for (int l = 0; l < L; ++l) {
        const _Float16* Ah = (l == 0) ? xh : (jk_h + (size_t)(l - 1) * H);
        int lda            = (l == 0) ? F : H * L;
        int K              = (l == 0) ? F : H;
        const _Float16* BT = (l == 0) ? w0comb : (wcomb + (size_t)(l - 1) * 512 * H);
        const float* gcB   = (l == 0) ? in_gc_b  : (convs_b + (size_t)(l - 1) * H);
        const float* liB   = (l == 0) ? in_lin_b : (lins_b  + (size_t)(l - 1) * H);

        gemm_dual<<<dual_blocks, 256, 0, stream>>>(Ah, lda, BT, K, liB, gcB,
                                                   lin_h, hw, N, m_tiles);
        aggregate_csr<<<agg_blocks, 256, 0, stream>>>(rowptr, count, sorted_meta,
                                                      dinv, hw, lin_h, jk_h + (size_t)l * H, N);
    }

    // 4) out = jk_h @ out_W + out_b
    gemm_out<<<out_blocks, 256, 0, stream>>>(jk_h, outWT, out_b, out, N);
}